// Round 11
// baseline (492.028 us; speedup 1.0000x reference)
//
#include <hip/hip_runtime.h>
#include <hip/hip_fp16.h>
#include <math.h>

#define NN 50000
#define NE 1600000
#define NBIN 512       // fine dst bins; one k_edge3 block owns one bin
#define DSTF 98        // dsts per bin; 512*98 = 50176 >= NN
#define NREP 8         // bucket replicas (XCD-local append regions)
#define PCAP 24        // per-(block,bin) LDS stage cap (mean 4, +10 sigma)
#define BCAPR 576      // per-(rep,bin) bucket cap (mean 391, +9 sigma)

__device__ __forceinline__ float wave_sum(float v) {
    #pragma unroll
    for (int off = 32; off > 0; off >>= 1) v += __shfl_xor(v, off, 64);
    return v;
}

// ---------------- K0a: GAT-side node precompute ----------------
// W in LDS; x tile staged coalesced into LDS; compute reads LDS only.
// t-loop MUST stay rolled (#pragma unroll 1): full unroll exposes 288
// ds_read_b128 whose results LLVM hoists -> >256 VGPR -> scratch spill
// (R8: 849us, R9: 557us, both with GB-scale FETCH/WRITE from spill).
__global__ __launch_bounds__(256) void k_node_gat(
    const float* __restrict__ x_local, const float* __restrict__ gat_w,
    const float* __restrict__ att_src, const float* __restrict__ att_dst,
    const float* __restrict__ nf, const float* __restrict__ coord,
    const float* __restrict__ fc1_w, const float* __restrict__ fc1_b,
    const float* __restrict__ fc2_w, const float* __restrict__ fc2_b,
    __half* __restrict__ xlh,
    float4* __restrict__ snode, float4* __restrict__ dnode,
    float* __restrict__ ps)
{
    __shared__ float wL[64 * 132];              // 33.8 KB W, [h][k] stride 132
    __shared__ float xt[32 * 128];              // 16 KB x tile (32 nodes)
    for (int f = threadIdx.x; f < 64 * 128; f += 256) {
        int h = f >> 7, k = f & 127;
        wL[h * 132 + k] = gat_w[f];
    }
    const int lane = threadIdx.x & 63;
    const int wid  = threadIdx.x >> 6;
    const float asv = att_src[lane];
    const float adv = att_dst[lane];
    const float4* wrow = (const float4*)(wL + lane * 132);
    float4* xts = (float4*)xt;
    const float4* xp = (const float4*)x_local;
    for (int base = blockIdx.x * 32; base < NN; base += gridDim.x * 32) {
        __syncthreads();                        // W staged / prev tile done
        #pragma unroll
        for (int k = 0; k < 4; k++) {
            int gi = base * 32 + (int)threadIdx.x + k * 256;
            if (gi < NN * 32) xts[threadIdx.x + k * 256] = xp[gi];
        }
        __syncthreads();
        float acc[8] = {0.f,0.f,0.f,0.f,0.f,0.f,0.f,0.f};
        const float4* xrow = (const float4*)(xt + wid * 8 * 128);
        #pragma unroll 1
        for (int t = 0; t < 32; t++) {
            float4 wv = wrow[t];                // per-lane ds_read_b128
            #pragma unroll
            for (int j = 0; j < 8; j++) {
                float4 xv = xrow[j * 32 + t];   // wave-uniform LDS broadcast
                acc[j] = fmaf(xv.x, wv.x, acc[j]);
                acc[j] = fmaf(xv.y, wv.y, acc[j]);
                acc[j] = fmaf(xv.z, wv.z, acc[j]);
                acc[j] = fmaf(xv.w, wv.w, acc[j]);
            }
        }
        float sv[8], dv[8];
        #pragma unroll
        for (int j = 0; j < 8; j++) {
            int n = base + wid * 8 + j;
            if (n < NN) xlh[(size_t)n * 64 + lane] = __float2half(acc[j]);
            sv[j] = wave_sum(acc[j] * asv);
            dv[j] = wave_sum(acc[j] * adv);
        }
        if (lane < 8) {
            int n = base + wid * 8 + lane;
            if (n < NN) {
                float svx = (lane==0)?sv[0]:(lane==1)?sv[1]:(lane==2)?sv[2]:(lane==3)?sv[3]
                           :(lane==4)?sv[4]:(lane==5)?sv[5]:(lane==6)?sv[6]:sv[7];
                float dvx = (lane==0)?dv[0]:(lane==1)?dv[1]:(lane==2)?dv[2]:(lane==3)?dv[3]
                           :(lane==4)?dv[4]:(lane==5)?dv[5]:(lane==6)?dv[6]:dv[7];
                float xvv[10];
                #pragma unroll
                for (int k = 0; k < 10; k++) xvv[k] = nf[n * 10 + k];
                float niv = fc2_b[0];
                #pragma unroll
                for (int j = 0; j < 10; j++) {
                    float h = fc1_b[j];
                    #pragma unroll
                    for (int k = 0; k < 10; k++) h = fmaf(xvv[k], fc1_w[j * 10 + k], h);
                    h = (h > 0.f) ? h : expm1f(h);
                    niv = fmaf(h, fc2_w[j], niv);
                }
                float cx = coord[2 * n], cy = coord[2 * n + 1];
                float es = svx + dvx;
                es = (es >= 0.f) ? es : 0.2f * es;
                snode[n] = make_float4(cx, cy, svx, niv);
                dnode[n] = make_float4(cx, cy, dvx, 0.f);
                ps[n] = __expf(es);
            }
        }
    }
}

// ---------------- K0b: GCN-side node precompute ----------------
__global__ __launch_bounds__(256) void k_node_gcn(
    const float* __restrict__ x_global, const float* __restrict__ gcn_w,
    __half* __restrict__ xgh)
{
    __shared__ float wL[64 * 132];
    __shared__ float xt[32 * 128];
    for (int f = threadIdx.x; f < 64 * 128; f += 256) {
        int h = f >> 7, k = f & 127;
        wL[h * 132 + k] = gcn_w[f];
    }
    const int lane = threadIdx.x & 63;
    const int wid  = threadIdx.x >> 6;
    const float4* wrow = (const float4*)(wL + lane * 132);
    float4* xts = (float4*)xt;
    const float4* xp = (const float4*)x_global;
    for (int base = blockIdx.x * 32; base < NN; base += gridDim.x * 32) {
        __syncthreads();
        #pragma unroll
        for (int k = 0; k < 4; k++) {
            int gi = base * 32 + (int)threadIdx.x + k * 256;
            if (gi < NN * 32) xts[threadIdx.x + k * 256] = xp[gi];
        }
        __syncthreads();
        float acc[8] = {0.f,0.f,0.f,0.f,0.f,0.f,0.f,0.f};
        const float4* xrow = (const float4*)(xt + wid * 8 * 128);
        #pragma unroll 1
        for (int t = 0; t < 32; t++) {
            float4 wv = wrow[t];
            #pragma unroll
            for (int j = 0; j < 8; j++) {
                float4 xv = xrow[j * 32 + t];
                acc[j] = fmaf(xv.x, wv.x, acc[j]);
                acc[j] = fmaf(xv.y, wv.y, acc[j]);
                acc[j] = fmaf(xv.z, wv.z, acc[j]);
                acc[j] = fmaf(xv.w, wv.w, acc[j]);
            }
        }
        #pragma unroll
        for (int j = 0; j < 8; j++) {
            int n = base + wid * 8 + j;
            if (n < NN) xgh[(size_t)n * 64 + lane] = __float2half(acc[j]);
        }
    }
}

// ---------------- P0: zero bucket counters ----------------
__global__ __launch_bounds__(256) void k_zerog(unsigned int* __restrict__ gcnt)
{
    int i = blockIdx.x * 256 + threadIdx.x;
    if (i < NREP * NBIN) gcnt[i] = 0u;
}

// ---------------- P1: LDS-staged radix partition into 512 fine bins ------
__global__ __launch_bounds__(256) void k_part2(
    const int* __restrict__ ei,
    unsigned int* __restrict__ bucket, unsigned int* __restrict__ gcnt)
{
    __shared__ unsigned int lcnt[NBIN];
    __shared__ unsigned int lbase[NBIN];
    __shared__ unsigned int lbuf[NBIN][PCAP];   // 512*24*4 = 48 KiB
    const int rep = blockIdx.x & 7;
    for (int t = threadIdx.x; t < NBIN; t += 256) lcnt[t] = 0u;
    __syncthreads();
    const int base = blockIdx.x * 2048;
    #pragma unroll
    for (int k = 0; k < 8; k++) {
        int i = base + k * 256 + threadIdx.x;
        if (i < NE) {
            int d = ei[NE + i];
            int s = ei[i];
            int b = d / DSTF;
            unsigned int pk = (unsigned int)s | ((unsigned int)(d - b * DSTF) << 16);
            unsigned int slot = atomicAdd(&lcnt[b], 1u);
            if (slot < PCAP) {
                lbuf[b][slot] = pk;
            } else {                            // ~never (+10 sigma); insurance
                unsigned int g = atomicAdd(&gcnt[rep * NBIN + b], 1u);
                if (g < BCAPR) bucket[(size_t)(rep * NBIN + b) * BCAPR + g] = pk;
            }
        }
    }
    __syncthreads();
    for (int t = threadIdx.x; t < NBIN; t += 256) {
        unsigned int n = lcnt[t];
        if (n > PCAP) n = PCAP;
        lcnt[t] = n;
        lbase[t] = n ? atomicAdd(&gcnt[rep * NBIN + t], n) : 0u;
    }
    __syncthreads();
    for (int t = threadIdx.x; t < NBIN; t += 256) {
        unsigned int n = lcnt[t];
        unsigned int gb = lbase[t];
        unsigned int* dst = bucket + (size_t)(rep * NBIN + t) * BCAPR;
        for (unsigned int e = 0; e < n; e++) {
            unsigned int g = gb + e;
            if (g < BCAPR) dst[g] = lbuf[t][e];
        }
    }
}

// ---------------- K1: per-bin edge pass, ZERO global atomics -------------
__global__ __launch_bounds__(512) void k_edge3(
    const unsigned int* __restrict__ bucket, const unsigned int* __restrict__ gcnt,
    const float4* __restrict__ snode, const float4* __restrict__ dnode,
    uint2* __restrict__ rec, unsigned int* __restrict__ offA,
    unsigned int* __restrict__ cntA, float* __restrict__ dis)
{
    const int bin = blockIdx.x;
    const int d0  = bin * DSTF;
    __shared__ unsigned int cnt[DSTF], off[DSTF], cur[DSTF], ews[DSTF];
    __shared__ float4 dnd[DSTF];
    __shared__ unsigned int segc[NREP];
    __shared__ unsigned int sm[128];
    __shared__ unsigned int wsum[8];
    __shared__ unsigned int sbase;
    for (int t = threadIdx.x; t < DSTF; t += 512) {
        cnt[t] = 0u; cur[t] = 0u; ews[t] = 0u;
        int d = d0 + t;
        dnd[t] = (d < NN) ? dnode[d] : make_float4(0.f, 0.f, 0.f, 0.f);
    }
    if (threadIdx.x < NREP) {
        unsigned int c = gcnt[threadIdx.x * NBIN + bin];
        segc[threadIdx.x] = (c > BCAPR) ? BCAPR : c;
    }
    unsigned int partial = 0u;
    for (int idx = threadIdx.x; idx < NREP * NBIN; idx += 512) {
        int b = idx & (NBIN - 1);
        if (b < bin) {
            unsigned int c = gcnt[(idx >> 9) * NBIN + b];
            partial += (c > BCAPR) ? BCAPR : c;
        }
    }
    #pragma unroll
    for (int o = 32; o > 0; o >>= 1) partial += __shfl_xor(partial, o, 64);
    if ((threadIdx.x & 63) == 0) wsum[threadIdx.x >> 6] = partial;
    __syncthreads();
    if (threadIdx.x == 0) {
        unsigned int a = 0;
        #pragma unroll
        for (int r = 0; r < 8; r++) a += wsum[r];
        sbase = a;
    }
    __syncthreads();
    #pragma unroll
    for (int r = 0; r < NREP; r++) {
        unsigned int c = segc[r];
        const unsigned int* bk = bucket + (size_t)(r * NBIN + bin) * BCAPR;
        for (unsigned int t = threadIdx.x; t < c; t += 512)
            atomicAdd(&cnt[bk[t] >> 16], 1u);
    }
    __syncthreads();
    if (threadIdx.x < 128) sm[threadIdx.x] = (threadIdx.x < DSTF) ? cnt[threadIdx.x] : 0u;
    __syncthreads();
    for (int o = 1; o < 128; o <<= 1) {
        unsigned int t = 0;
        if (threadIdx.x < 128 && threadIdx.x >= o) t = sm[threadIdx.x - o];
        __syncthreads();
        if (threadIdx.x < 128) sm[threadIdx.x] += t;
        __syncthreads();
    }
    if (threadIdx.x < DSTF) off[threadIdx.x] = sbase + sm[threadIdx.x] - cnt[threadIdx.x];
    __syncthreads();
    #pragma unroll
    for (int r = 0; r < NREP; r++) {
        unsigned int c = segc[r];
        const unsigned int* bk = bucket + (size_t)(r * NBIN + bin) * BCAPR;
        for (unsigned int t = threadIdx.x; t < c; t += 512) {
            unsigned int pk = bk[t];
            int dl = (int)(pk >> 16);
            int s  = (int)(pk & 0xFFFFu);
            float4 sv = snode[s];
            float4 dv = dnd[dl];
            float dx = sv.x - dv.x, dy = sv.y - dv.y;
            float gw = __expf((dx * dx + dy * dy) * (-1.0f / 1800.0f));
            float tt = fmaf(gw, 1.0f + sv.w, -1.0f);
            float sg = 1.0f / (1.0f + __expf(-tt));
            float w  = fmaf(1.9f, sg, 0.1f);
            float e  = sv.z + dv.z;
            e = (e >= 0.f) ? e : 0.2f * e;
            float ewv = (w >= 0.2f) ? w : 0.0f;
            float p = (ewv != 0.f) ? __expf(e) : 0.0f;
            unsigned int rk = atomicAdd(&cur[dl], 1u);
            atomicAdd(&ews[dl], (unsigned int)(ewv * 16777216.0f + 0.5f));
            __half2 h = __floats2half2_rn(p, ewv);
            rec[off[dl] + rk] = make_uint2((unsigned int)s, *(unsigned int*)&h);
        }
    }
    __syncthreads();
    for (int t = threadIdx.x; t < DSTF; t += 512) {
        int d = d0 + t;
        if (d < NN) {
            offA[d] = off[t];
            cntA[d] = cnt[t];
            dis[d]  = rsqrtf(1.0f + (float)ews[t] * (1.0f / 16777216.0f));
        }
    }
}

// ---------------- K3: fused GAT+GCN gather over compact CSR --------------
__global__ __launch_bounds__(256) void k_gather2(
    const __half* __restrict__ xlh, const __half* __restrict__ xgh,
    const float* __restrict__ ps, const float* __restrict__ dis,
    const unsigned int* __restrict__ offA, const unsigned int* __restrict__ cntA,
    const uint2* __restrict__ rec,
    const float* __restrict__ gat_b, const float* __restrict__ gcn_b,
    uint2* __restrict__ catLh, uint2* __restrict__ catGh)
{
    const int lane = threadIdx.x & 63;
    const int wid  = threadIdx.x >> 6;
    const int eg   = lane >> 4;
    const int fi   = (lane & 15) << 2;
    const float4 gb = *(const float4*)(gat_b + fi);
    const float4 cb = *(const float4*)(gcn_b + fi);
    const float g0 = (eg == 0) ? 1.0f : 0.0f;
    for (int n = blockIdx.x * 4 + wid; n < NN; n += gridDim.x * 4) {
        float psv = ps[n] * g0;
        float dd = dis[n];
        int beg = (int)offA[n];
        int end = beg + (int)cntA[n];
        uint2 us = *(const uint2*)(xlh + (size_t)n * 64 + fi);
        uint2 ug = *(const uint2*)(xgh + (size_t)n * 64 + fi);
        float2 s01 = __half22float2(*(const __half2*)&us.x);
        float2 s23 = __half22float2(*(const __half2*)&us.y);
        float2 q01 = __half22float2(*(const __half2*)&ug.x);
        float2 q23 = __half22float2(*(const __half2*)&ug.y);
        float4 aL, aC;
        aL.x = psv * s01.x; aL.y = psv * s01.y; aL.z = psv * s23.x; aL.w = psv * s23.y;
        float sw = dd * g0;
        aC.x = sw * q01.x; aC.y = sw * q01.y; aC.z = sw * q23.x; aC.w = sw * q23.y;
        float den = psv;
        int j = beg + eg;
        for (; j + 4 < end; j += 8) {
            uint2 r0 = rec[j];
            uint2 r1 = rec[j + 4];
            int s0 = (int)r0.x;
            int s1 = (int)r1.x;
            float2 pc0 = __half22float2(*(const __half2*)&r0.y);
            float2 pc1 = __half22float2(*(const __half2*)&r1.y);
            float c0 = dis[s0] * pc0.y;
            float c1 = dis[s1] * pc1.y;
            uint2 ul0 = *(const uint2*)(xlh + (size_t)s0 * 64 + fi);
            uint2 ul1 = *(const uint2*)(xlh + (size_t)s1 * 64 + fi);
            uint2 ug0 = *(const uint2*)(xgh + (size_t)s0 * 64 + fi);
            uint2 ug1 = *(const uint2*)(xgh + (size_t)s1 * 64 + fi);
            float2 l0a = __half22float2(*(const __half2*)&ul0.x);
            float2 l0b = __half22float2(*(const __half2*)&ul0.y);
            float2 l1a = __half22float2(*(const __half2*)&ul1.x);
            float2 l1b = __half22float2(*(const __half2*)&ul1.y);
            float2 g0a = __half22float2(*(const __half2*)&ug0.x);
            float2 g0b = __half22float2(*(const __half2*)&ug0.y);
            float2 g1a = __half22float2(*(const __half2*)&ug1.x);
            float2 g1b = __half22float2(*(const __half2*)&ug1.y);
            aL.x = fmaf(pc0.x, l0a.x, aL.x); aL.y = fmaf(pc0.x, l0a.y, aL.y);
            aL.z = fmaf(pc0.x, l0b.x, aL.z); aL.w = fmaf(pc0.x, l0b.y, aL.w);
            aL.x = fmaf(pc1.x, l1a.x, aL.x); aL.y = fmaf(pc1.x, l1a.y, aL.y);
            aL.z = fmaf(pc1.x, l1b.x, aL.z); aL.w = fmaf(pc1.x, l1b.y, aL.w);
            aC.x = fmaf(c0, g0a.x, aC.x); aC.y = fmaf(c0, g0a.y, aC.y);
            aC.z = fmaf(c0, g0b.x, aC.z); aC.w = fmaf(c0, g0b.y, aC.w);
            aC.x = fmaf(c1, g1a.x, aC.x); aC.y = fmaf(c1, g1a.y, aC.y);
            aC.z = fmaf(c1, g1b.x, aC.z); aC.w = fmaf(c1, g1b.y, aC.w);
            den += pc0.x + pc1.x;
        }
        if (j < end) {
            uint2 r0 = rec[j];
            int s0 = (int)r0.x;
            float2 pc0 = __half22float2(*(const __half2*)&r0.y);
            float c0 = dis[s0] * pc0.y;
            uint2 ul0 = *(const uint2*)(xlh + (size_t)s0 * 64 + fi);
            uint2 ug0 = *(const uint2*)(xgh + (size_t)s0 * 64 + fi);
            float2 l0a = __half22float2(*(const __half2*)&ul0.x);
            float2 l0b = __half22float2(*(const __half2*)&ul0.y);
            float2 g0a = __half22float2(*(const __half2*)&ug0.x);
            float2 g0b = __half22float2(*(const __half2*)&ug0.y);
            aL.x = fmaf(pc0.x, l0a.x, aL.x); aL.y = fmaf(pc0.x, l0a.y, aL.y);
            aL.z = fmaf(pc0.x, l0b.x, aL.z); aL.w = fmaf(pc0.x, l0b.y, aL.w);
            aC.x = fmaf(c0, g0a.x, aC.x); aC.y = fmaf(c0, g0a.y, aC.y);
            aC.z = fmaf(c0, g0b.x, aC.z); aC.w = fmaf(c0, g0b.y, aC.w);
            den += pc0.x;
        }
        #pragma unroll
        for (int m = 16; m <= 32; m <<= 1) {
            aL.x += __shfl_xor(aL.x, m, 64); aL.y += __shfl_xor(aL.y, m, 64);
            aL.z += __shfl_xor(aL.z, m, 64); aL.w += __shfl_xor(aL.w, m, 64);
            aC.x += __shfl_xor(aC.x, m, 64); aC.y += __shfl_xor(aC.y, m, 64);
            aC.z += __shfl_xor(aC.z, m, 64); aC.w += __shfl_xor(aC.w, m, 64);
            den  += __shfl_xor(den,  m, 64);
        }
        if (eg == 0) {
            float rd = 1.0f / den;
            float4 la, ga;
            la.x = fmaf(aL.x, rd, gb.x); la.y = fmaf(aL.y, rd, gb.y);
            la.z = fmaf(aL.z, rd, gb.z); la.w = fmaf(aL.w, rd, gb.w);
            la.x = (la.x > 0.f) ? la.x : expm1f(la.x);
            la.y = (la.y > 0.f) ? la.y : expm1f(la.y);
            la.z = (la.z > 0.f) ? la.z : expm1f(la.z);
            la.w = (la.w > 0.f) ? la.w : expm1f(la.w);
            ga.x = fmaxf(fmaf(dd, aC.x, cb.x), 0.f);
            ga.y = fmaxf(fmaf(dd, aC.y, cb.y), 0.f);
            ga.z = fmaxf(fmaf(dd, aC.z, cb.z), 0.f);
            ga.w = fmaxf(fmaf(dd, aC.w, cb.w), 0.f);
            __half2 l01 = __floats2half2_rn(la.x, la.y);
            __half2 l23 = __floats2half2_rn(la.z, la.w);
            __half2 g01h = __floats2half2_rn(ga.x, ga.y);
            __half2 g23h = __floats2half2_rn(ga.z, ga.w);
            catLh[(size_t)n * 16 + (fi >> 2)] =
                make_uint2(*(unsigned int*)&l01, *(unsigned int*)&l23);
            catGh[(size_t)n * 16 + (fi >> 2)] =
                make_uint2(*(unsigned int*)&g01h, *(unsigned int*)&g23h);
        }
    }
}

// ---------------- K4: fusion head, 8 threads per node ----------------
// R10: one-thread-per-node = 782 waves over 1024 SIMDs (8.5% occupancy,
// serial 8192-FMA chain) -> 70us. Split hidden dim 8-way: thread handles
// 8 of 64 hid units; 400K threads = 6250 waves (~6/SIMD); final dot
// reduced across the 8 adjacent lanes with 3 shuffles. Cat-line reads
// become 8-lane broadcasts (one 128B line per node per kb).
__global__ __launch_bounds__(256) void k_fuse(
    const uint2* __restrict__ catLh, const uint2* __restrict__ catGh,
    const float* __restrict__ fus_w1, const float* __restrict__ fus_b1,
    const float* __restrict__ fus_w2, const float* __restrict__ fus_b2,
    float* __restrict__ out)
{
    int idx = blockIdx.x * 256 + threadIdx.x;
    int n = idx >> 3;
    int q = idx & 7;
    if (n >= NN) return;
    const uint2* rl = catLh + (size_t)n * 16;
    const uint2* rg = catGh + (size_t)n * 16;
    float hid[8];
    #pragma unroll
    for (int j = 0; j < 8; j++) hid[j] = fus_b1[q * 8 + j];
    for (int kb = 0; kb < 16; kb++) {
        uint2 u = rl[kb];
        float2 f0 = __half22float2(*(const __half2*)&u.x);
        float2 f1 = __half22float2(*(const __half2*)&u.y);
        #pragma unroll
        for (int j = 0; j < 8; j++) {
            const float* wr = fus_w1 + (size_t)(q * 8 + j) * 128 + kb * 4;
            hid[j] = fmaf(wr[0], f0.x, hid[j]);
            hid[j] = fmaf(wr[1], f0.y, hid[j]);
            hid[j] = fmaf(wr[2], f1.x, hid[j]);
            hid[j] = fmaf(wr[3], f1.y, hid[j]);
        }
    }
    for (int kb = 0; kb < 16; kb++) {
        uint2 u = rg[kb];
        float2 f0 = __half22float2(*(const __half2*)&u.x);
        float2 f1 = __half22float2(*(const __half2*)&u.y);
        #pragma unroll
        for (int j = 0; j < 8; j++) {
            const float* wr = fus_w1 + (size_t)(q * 8 + j) * 128 + 64 + kb * 4;
            hid[j] = fmaf(wr[0], f0.x, hid[j]);
            hid[j] = fmaf(wr[1], f0.y, hid[j]);
            hid[j] = fmaf(wr[2], f1.x, hid[j]);
            hid[j] = fmaf(wr[3], f1.y, hid[j]);
        }
    }
    float acc = 0.f;
    #pragma unroll
    for (int j = 0; j < 8; j++)
        acc = fmaf(fmaxf(hid[j], 0.f), fus_w2[q * 8 + j], acc);
    acc += __shfl_xor(acc, 1, 64);
    acc += __shfl_xor(acc, 2, 64);
    acc += __shfl_xor(acc, 4, 64);
    if (q == 0) out[n] = acc + fus_b2[0];
}

extern "C" void kernel_launch(void* const* d_in, const int* in_sizes, int n_in,
                              void* d_out, int out_size, void* d_ws, size_t ws_size,
                              hipStream_t stream)
{
    const float* x_local  = (const float*)d_in[0];
    const float* x_global = (const float*)d_in[1];
    const float* nf       = (const float*)d_in[2];
    const float* coord    = (const float*)d_in[3];
    const int*   ei       = (const int*)d_in[4];
    const float* fc1_w    = (const float*)d_in[5];
    const float* fc1_b    = (const float*)d_in[6];
    const float* fc2_w    = (const float*)d_in[7];
    const float* fc2_b    = (const float*)d_in[8];
    const float* gat_w    = (const float*)d_in[9];
    const float* att_src  = (const float*)d_in[10];
    const float* att_dst  = (const float*)d_in[11];
    const float* gat_b    = (const float*)d_in[12];
    const float* gcn_w    = (const float*)d_in[13];
    const float* gcn_b    = (const float*)d_in[14];
    const float* fus_w1   = (const float*)d_in[15];
    const float* fus_b1   = (const float*)d_in[16];
    const float* fus_w2   = (const float*)d_in[17];
    const float* fus_b2   = (const float*)d_in[18];
    float* out = (float*)d_out;

    char* ws = (char*)d_ws;
    uint2*  rec  = (uint2*) (ws);                       // compact CSR 1.6M*8 = 12,800,000
    __half* xlh  = (__half*)(ws + 12800000);            //  6,400,000
    __half* xgh  = (__half*)(ws + 19200000);            //  6,400,000
    uint2*  catLh= (uint2*) (ws + 25600000);            //  6,400,000
    uint2*  catGh= (uint2*) (ws + 32000000);            //  6,400,000
    // bucket OVERLAYS cat region: dead before k_gather2 writes cat*
    unsigned int* bucket = (unsigned int*)(ws + 25600000); // 8*512*576*4 = 9,437,184
    float4* snode= (float4*)(ws + 38400000);            //    800,000
    float4* dnode= (float4*)(ws + 39200000);            //    800,000
    unsigned int* offA = (unsigned int*)(ws + 40000000);//    200,000
    unsigned int* cntA = (unsigned int*)(ws + 40200000);//    200,000
    float*  dis  = (float*) (ws + 40400000);            //    200,000
    float*  ps   = (float*) (ws + 40600000);            //    200,000
    unsigned int* gcnt = (unsigned int*)(ws + 40800000);//     16,384 -> end ~40.82 MB
    (void)in_sizes; (void)n_in; (void)out_size; (void)ws_size;

    k_zerog<<<(NREP * NBIN + 255) / 256, 256, 0, stream>>>(gcnt);
    k_part2<<<782, 256, 0, stream>>>(ei, bucket, gcnt);   // 782*2048 >= NE
    k_node_gat<<<782, 256, 0, stream>>>(x_local, gat_w, att_src, att_dst,
                                        nf, coord, fc1_w, fc1_b, fc2_w, fc2_b,
                                        xlh, snode, dnode, ps);
    k_node_gcn<<<782, 256, 0, stream>>>(x_global, gcn_w, xgh);
    k_edge3<<<NBIN, 512, 0, stream>>>(bucket, gcnt, snode, dnode,
                                      rec, offA, cntA, dis);
    k_gather2<<<3125, 256, 0, stream>>>(xlh, xgh, ps, dis, offA, cntA, rec,
                                        gat_b, gcn_b, catLh, catGh);
    k_fuse<<<(NN * 8 + 255) / 256, 256, 0, stream>>>(catLh, catGh,
                                                     fus_w1, fus_b1, fus_w2, fus_b2, out);
}

// Round 12
// 412.667 us; speedup vs baseline: 1.1923x; 1.1923x over previous
//
#include <hip/hip_runtime.h>
#include <hip/hip_fp16.h>
#include <math.h>

#define NN 50000
#define NE 1600000
#define NBIN 512       // fine dst bins; one k_edge3 block owns one bin
#define DSTF 98        // dsts per bin; 512*98 = 50176 >= NN
#define NREP 8         // bucket replicas (XCD-local append regions)
#define PCAP 24        // per-(block,bin) LDS stage cap (mean 4, +10 sigma)
#define BCAPR 576      // per-(rep,bin) bucket cap (mean 391, +9 sigma)

__device__ __forceinline__ float wave_sum(float v) {
    #pragma unroll
    for (int off = 32; off > 0; off >>= 1) v += __shfl_xor(v, off, 64);
    return v;
}

// ---------------- K0a: GAT-side node precompute ----------------
// W in LDS; x tile staged coalesced into LDS; compute reads LDS only.
// t-loop MUST stay rolled (#pragma unroll 1): full unroll exposes 288
// ds_read_b128 whose results LLVM hoists -> >256 VGPR -> scratch spill
// (R8: 849us, R9: 557us, both with GB-scale FETCH/WRITE from spill).
__global__ __launch_bounds__(256) void k_node_gat(
    const float* __restrict__ x_local, const float* __restrict__ gat_w,
    const float* __restrict__ att_src, const float* __restrict__ att_dst,
    const float* __restrict__ nf, const float* __restrict__ coord,
    const float* __restrict__ fc1_w, const float* __restrict__ fc1_b,
    const float* __restrict__ fc2_w, const float* __restrict__ fc2_b,
    __half* __restrict__ xlh,
    float4* __restrict__ snode, float4* __restrict__ dnode,
    float* __restrict__ ps)
{
    __shared__ float wL[64 * 132];              // 33.8 KB W, [h][k] stride 132
    __shared__ float xt[32 * 128];              // 16 KB x tile (32 nodes)
    for (int f = threadIdx.x; f < 64 * 128; f += 256) {
        int h = f >> 7, k = f & 127;
        wL[h * 132 + k] = gat_w[f];
    }
    const int lane = threadIdx.x & 63;
    const int wid  = threadIdx.x >> 6;
    const float asv = att_src[lane];
    const float adv = att_dst[lane];
    const float4* wrow = (const float4*)(wL + lane * 132);
    float4* xts = (float4*)xt;
    const float4* xp = (const float4*)x_local;
    for (int base = blockIdx.x * 32; base < NN; base += gridDim.x * 32) {
        __syncthreads();                        // W staged / prev tile done
        #pragma unroll
        for (int k = 0; k < 4; k++) {
            int gi = base * 32 + (int)threadIdx.x + k * 256;
            if (gi < NN * 32) xts[threadIdx.x + k * 256] = xp[gi];
        }
        __syncthreads();
        float acc[8] = {0.f,0.f,0.f,0.f,0.f,0.f,0.f,0.f};
        const float4* xrow = (const float4*)(xt + wid * 8 * 128);
        #pragma unroll 1
        for (int t = 0; t < 32; t++) {
            float4 wv = wrow[t];                // per-lane ds_read_b128
            #pragma unroll
            for (int j = 0; j < 8; j++) {
                float4 xv = xrow[j * 32 + t];   // wave-uniform LDS broadcast
                acc[j] = fmaf(xv.x, wv.x, acc[j]);
                acc[j] = fmaf(xv.y, wv.y, acc[j]);
                acc[j] = fmaf(xv.z, wv.z, acc[j]);
                acc[j] = fmaf(xv.w, wv.w, acc[j]);
            }
        }
        float sv[8], dv[8];
        #pragma unroll
        for (int j = 0; j < 8; j++) {
            int n = base + wid * 8 + j;
            if (n < NN) xlh[(size_t)n * 64 + lane] = __float2half(acc[j]);
            sv[j] = wave_sum(acc[j] * asv);
            dv[j] = wave_sum(acc[j] * adv);
        }
        if (lane < 8) {
            int n = base + wid * 8 + lane;
            if (n < NN) {
                float svx = (lane==0)?sv[0]:(lane==1)?sv[1]:(lane==2)?sv[2]:(lane==3)?sv[3]
                           :(lane==4)?sv[4]:(lane==5)?sv[5]:(lane==6)?sv[6]:sv[7];
                float dvx = (lane==0)?dv[0]:(lane==1)?dv[1]:(lane==2)?dv[2]:(lane==3)?dv[3]
                           :(lane==4)?dv[4]:(lane==5)?dv[5]:(lane==6)?dv[6]:dv[7];
                float xvv[10];
                #pragma unroll
                for (int k = 0; k < 10; k++) xvv[k] = nf[n * 10 + k];
                float niv = fc2_b[0];
                #pragma unroll
                for (int j = 0; j < 10; j++) {
                    float h = fc1_b[j];
                    #pragma unroll
                    for (int k = 0; k < 10; k++) h = fmaf(xvv[k], fc1_w[j * 10 + k], h);
                    h = (h > 0.f) ? h : expm1f(h);
                    niv = fmaf(h, fc2_w[j], niv);
                }
                float cx = coord[2 * n], cy = coord[2 * n + 1];
                float es = svx + dvx;
                es = (es >= 0.f) ? es : 0.2f * es;
                snode[n] = make_float4(cx, cy, svx, niv);
                dnode[n] = make_float4(cx, cy, dvx, 0.f);
                ps[n] = __expf(es);
            }
        }
    }
}

// ---------------- K0b: GCN-side node precompute ----------------
__global__ __launch_bounds__(256) void k_node_gcn(
    const float* __restrict__ x_global, const float* __restrict__ gcn_w,
    __half* __restrict__ xgh)
{
    __shared__ float wL[64 * 132];
    __shared__ float xt[32 * 128];
    for (int f = threadIdx.x; f < 64 * 128; f += 256) {
        int h = f >> 7, k = f & 127;
        wL[h * 132 + k] = gcn_w[f];
    }
    const int lane = threadIdx.x & 63;
    const int wid  = threadIdx.x >> 6;
    const float4* wrow = (const float4*)(wL + lane * 132);
    float4* xts = (float4*)xt;
    const float4* xp = (const float4*)x_global;
    for (int base = blockIdx.x * 32; base < NN; base += gridDim.x * 32) {
        __syncthreads();
        #pragma unroll
        for (int k = 0; k < 4; k++) {
            int gi = base * 32 + (int)threadIdx.x + k * 256;
            if (gi < NN * 32) xts[threadIdx.x + k * 256] = xp[gi];
        }
        __syncthreads();
        float acc[8] = {0.f,0.f,0.f,0.f,0.f,0.f,0.f,0.f};
        const float4* xrow = (const float4*)(xt + wid * 8 * 128);
        #pragma unroll 1
        for (int t = 0; t < 32; t++) {
            float4 wv = wrow[t];
            #pragma unroll
            for (int j = 0; j < 8; j++) {
                float4 xv = xrow[j * 32 + t];
                acc[j] = fmaf(xv.x, wv.x, acc[j]);
                acc[j] = fmaf(xv.y, wv.y, acc[j]);
                acc[j] = fmaf(xv.z, wv.z, acc[j]);
                acc[j] = fmaf(xv.w, wv.w, acc[j]);
            }
        }
        #pragma unroll
        for (int j = 0; j < 8; j++) {
            int n = base + wid * 8 + j;
            if (n < NN) xgh[(size_t)n * 64 + lane] = __float2half(acc[j]);
        }
    }
}

// ---------------- P0: zero bucket counters ----------------
__global__ __launch_bounds__(256) void k_zerog(unsigned int* __restrict__ gcnt)
{
    int i = blockIdx.x * 256 + threadIdx.x;
    if (i < NREP * NBIN) gcnt[i] = 0u;
}

// ---------------- P1: LDS-staged radix partition into 512 fine bins ------
__global__ __launch_bounds__(256) void k_part2(
    const int* __restrict__ ei,
    unsigned int* __restrict__ bucket, unsigned int* __restrict__ gcnt)
{
    __shared__ unsigned int lcnt[NBIN];
    __shared__ unsigned int lbase[NBIN];
    __shared__ unsigned int lbuf[NBIN][PCAP];   // 512*24*4 = 48 KiB
    const int rep = blockIdx.x & 7;
    for (int t = threadIdx.x; t < NBIN; t += 256) lcnt[t] = 0u;
    __syncthreads();
    const int base = blockIdx.x * 2048;
    #pragma unroll
    for (int k = 0; k < 8; k++) {
        int i = base + k * 256 + threadIdx.x;
        if (i < NE) {
            int d = ei[NE + i];
            int s = ei[i];
            int b = d / DSTF;
            unsigned int pk = (unsigned int)s | ((unsigned int)(d - b * DSTF) << 16);
            unsigned int slot = atomicAdd(&lcnt[b], 1u);
            if (slot < PCAP) {
                lbuf[b][slot] = pk;
            } else {                            // ~never (+10 sigma); insurance
                unsigned int g = atomicAdd(&gcnt[rep * NBIN + b], 1u);
                if (g < BCAPR) bucket[(size_t)(rep * NBIN + b) * BCAPR + g] = pk;
            }
        }
    }
    __syncthreads();
    for (int t = threadIdx.x; t < NBIN; t += 256) {
        unsigned int n = lcnt[t];
        if (n > PCAP) n = PCAP;
        lcnt[t] = n;
        lbase[t] = n ? atomicAdd(&gcnt[rep * NBIN + t], n) : 0u;
    }
    __syncthreads();
    for (int t = threadIdx.x; t < NBIN; t += 256) {
        unsigned int n = lcnt[t];
        unsigned int gb = lbase[t];
        unsigned int* dst = bucket + (size_t)(rep * NBIN + t) * BCAPR;
        for (unsigned int e = 0; e < n; e++) {
            unsigned int g = gb + e;
            if (g < BCAPR) dst[g] = lbuf[t][e];
        }
    }
}

// ---------------- K1: per-bin edge pass, ZERO global atomics -------------
__global__ __launch_bounds__(512) void k_edge3(
    const unsigned int* __restrict__ bucket, const unsigned int* __restrict__ gcnt,
    const float4* __restrict__ snode, const float4* __restrict__ dnode,
    uint2* __restrict__ rec, unsigned int* __restrict__ offA,
    unsigned int* __restrict__ cntA, float* __restrict__ dis)
{
    const int bin = blockIdx.x;
    const int d0  = bin * DSTF;
    __shared__ unsigned int cnt[DSTF], off[DSTF], cur[DSTF], ews[DSTF];
    __shared__ float4 dnd[DSTF];
    __shared__ unsigned int segc[NREP];
    __shared__ unsigned int sm[128];
    __shared__ unsigned int wsum[8];
    __shared__ unsigned int sbase;
    for (int t = threadIdx.x; t < DSTF; t += 512) {
        cnt[t] = 0u; cur[t] = 0u; ews[t] = 0u;
        int d = d0 + t;
        dnd[t] = (d < NN) ? dnode[d] : make_float4(0.f, 0.f, 0.f, 0.f);
    }
    if (threadIdx.x < NREP) {
        unsigned int c = gcnt[threadIdx.x * NBIN + bin];
        segc[threadIdx.x] = (c > BCAPR) ? BCAPR : c;
    }
    unsigned int partial = 0u;
    for (int idx = threadIdx.x; idx < NREP * NBIN; idx += 512) {
        int b = idx & (NBIN - 1);
        if (b < bin) {
            unsigned int c = gcnt[(idx >> 9) * NBIN + b];
            partial += (c > BCAPR) ? BCAPR : c;
        }
    }
    #pragma unroll
    for (int o = 32; o > 0; o >>= 1) partial += __shfl_xor(partial, o, 64);
    if ((threadIdx.x & 63) == 0) wsum[threadIdx.x >> 6] = partial;
    __syncthreads();
    if (threadIdx.x == 0) {
        unsigned int a = 0;
        #pragma unroll
        for (int r = 0; r < 8; r++) a += wsum[r];
        sbase = a;
    }
    __syncthreads();
    #pragma unroll
    for (int r = 0; r < NREP; r++) {
        unsigned int c = segc[r];
        const unsigned int* bk = bucket + (size_t)(r * NBIN + bin) * BCAPR;
        for (unsigned int t = threadIdx.x; t < c; t += 512)
            atomicAdd(&cnt[bk[t] >> 16], 1u);
    }
    __syncthreads();
    if (threadIdx.x < 128) sm[threadIdx.x] = (threadIdx.x < DSTF) ? cnt[threadIdx.x] : 0u;
    __syncthreads();
    for (int o = 1; o < 128; o <<= 1) {
        unsigned int t = 0;
        if (threadIdx.x < 128 && threadIdx.x >= o) t = sm[threadIdx.x - o];
        __syncthreads();
        if (threadIdx.x < 128) sm[threadIdx.x] += t;
        __syncthreads();
    }
    if (threadIdx.x < DSTF) off[threadIdx.x] = sbase + sm[threadIdx.x] - cnt[threadIdx.x];
    __syncthreads();
    #pragma unroll
    for (int r = 0; r < NREP; r++) {
        unsigned int c = segc[r];
        const unsigned int* bk = bucket + (size_t)(r * NBIN + bin) * BCAPR;
        for (unsigned int t = threadIdx.x; t < c; t += 512) {
            unsigned int pk = bk[t];
            int dl = (int)(pk >> 16);
            int s  = (int)(pk & 0xFFFFu);
            float4 sv = snode[s];
            float4 dv = dnd[dl];
            float dx = sv.x - dv.x, dy = sv.y - dv.y;
            float gw = __expf((dx * dx + dy * dy) * (-1.0f / 1800.0f));
            float tt = fmaf(gw, 1.0f + sv.w, -1.0f);
            float sg = 1.0f / (1.0f + __expf(-tt));
            float w  = fmaf(1.9f, sg, 0.1f);
            float e  = sv.z + dv.z;
            e = (e >= 0.f) ? e : 0.2f * e;
            float ewv = (w >= 0.2f) ? w : 0.0f;
            float p = (ewv != 0.f) ? __expf(e) : 0.0f;
            unsigned int rk = atomicAdd(&cur[dl], 1u);
            atomicAdd(&ews[dl], (unsigned int)(ewv * 16777216.0f + 0.5f));
            __half2 h = __floats2half2_rn(p, ewv);
            rec[off[dl] + rk] = make_uint2((unsigned int)s, *(unsigned int*)&h);
        }
    }
    __syncthreads();
    for (int t = threadIdx.x; t < DSTF; t += 512) {
        int d = d0 + t;
        if (d < NN) {
            offA[d] = off[t];
            cntA[d] = cnt[t];
            dis[d]  = rsqrtf(1.0f + (float)ews[t] * (1.0f / 16777216.0f));
        }
    }
}

// ---------------- K3: fused GAT+GCN gather over compact CSR --------------
__global__ __launch_bounds__(256) void k_gather2(
    const __half* __restrict__ xlh, const __half* __restrict__ xgh,
    const float* __restrict__ ps, const float* __restrict__ dis,
    const unsigned int* __restrict__ offA, const unsigned int* __restrict__ cntA,
    const uint2* __restrict__ rec,
    const float* __restrict__ gat_b, const float* __restrict__ gcn_b,
    uint2* __restrict__ catLh, uint2* __restrict__ catGh)
{
    const int lane = threadIdx.x & 63;
    const int wid  = threadIdx.x >> 6;
    const int eg   = lane >> 4;
    const int fi   = (lane & 15) << 2;
    const float4 gb = *(const float4*)(gat_b + fi);
    const float4 cb = *(const float4*)(gcn_b + fi);
    const float g0 = (eg == 0) ? 1.0f : 0.0f;
    for (int n = blockIdx.x * 4 + wid; n < NN; n += gridDim.x * 4) {
        float psv = ps[n] * g0;
        float dd = dis[n];
        int beg = (int)offA[n];
        int end = beg + (int)cntA[n];
        uint2 us = *(const uint2*)(xlh + (size_t)n * 64 + fi);
        uint2 ug = *(const uint2*)(xgh + (size_t)n * 64 + fi);
        float2 s01 = __half22float2(*(const __half2*)&us.x);
        float2 s23 = __half22float2(*(const __half2*)&us.y);
        float2 q01 = __half22float2(*(const __half2*)&ug.x);
        float2 q23 = __half22float2(*(const __half2*)&ug.y);
        float4 aL, aC;
        aL.x = psv * s01.x; aL.y = psv * s01.y; aL.z = psv * s23.x; aL.w = psv * s23.y;
        float sw = dd * g0;
        aC.x = sw * q01.x; aC.y = sw * q01.y; aC.z = sw * q23.x; aC.w = sw * q23.y;
        float den = psv;
        int j = beg + eg;
        for (; j + 4 < end; j += 8) {
            uint2 r0 = rec[j];
            uint2 r1 = rec[j + 4];
            int s0 = (int)r0.x;
            int s1 = (int)r1.x;
            float2 pc0 = __half22float2(*(const __half2*)&r0.y);
            float2 pc1 = __half22float2(*(const __half2*)&r1.y);
            float c0 = dis[s0] * pc0.y;
            float c1 = dis[s1] * pc1.y;
            uint2 ul0 = *(const uint2*)(xlh + (size_t)s0 * 64 + fi);
            uint2 ul1 = *(const uint2*)(xlh + (size_t)s1 * 64 + fi);
            uint2 ug0 = *(const uint2*)(xgh + (size_t)s0 * 64 + fi);
            uint2 ug1 = *(const uint2*)(xgh + (size_t)s1 * 64 + fi);
            float2 l0a = __half22float2(*(const __half2*)&ul0.x);
            float2 l0b = __half22float2(*(const __half2*)&ul0.y);
            float2 l1a = __half22float2(*(const __half2*)&ul1.x);
            float2 l1b = __half22float2(*(const __half2*)&ul1.y);
            float2 g0a = __half22float2(*(const __half2*)&ug0.x);
            float2 g0b = __half22float2(*(const __half2*)&ug0.y);
            float2 g1a = __half22float2(*(const __half2*)&ug1.x);
            float2 g1b = __half22float2(*(const __half2*)&ug1.y);
            aL.x = fmaf(pc0.x, l0a.x, aL.x); aL.y = fmaf(pc0.x, l0a.y, aL.y);
            aL.z = fmaf(pc0.x, l0b.x, aL.z); aL.w = fmaf(pc0.x, l0b.y, aL.w);
            aL.x = fmaf(pc1.x, l1a.x, aL.x); aL.y = fmaf(pc1.x, l1a.y, aL.y);
            aL.z = fmaf(pc1.x, l1b.x, aL.z); aL.w = fmaf(pc1.x, l1b.y, aL.w);
            aC.x = fmaf(c0, g0a.x, aC.x); aC.y = fmaf(c0, g0a.y, aC.y);
            aC.z = fmaf(c0, g0b.x, aC.z); aC.w = fmaf(c0, g0b.y, aC.w);
            aC.x = fmaf(c1, g1a.x, aC.x); aC.y = fmaf(c1, g1a.y, aC.y);
            aC.z = fmaf(c1, g1b.x, aC.z); aC.w = fmaf(c1, g1b.y, aC.w);
            den += pc0.x + pc1.x;
        }
        if (j < end) {
            uint2 r0 = rec[j];
            int s0 = (int)r0.x;
            float2 pc0 = __half22float2(*(const __half2*)&r0.y);
            float c0 = dis[s0] * pc0.y;
            uint2 ul0 = *(const uint2*)(xlh + (size_t)s0 * 64 + fi);
            uint2 ug0 = *(const uint2*)(xgh + (size_t)s0 * 64 + fi);
            float2 l0a = __half22float2(*(const __half2*)&ul0.x);
            float2 l0b = __half22float2(*(const __half2*)&ul0.y);
            float2 g0a = __half22float2(*(const __half2*)&ug0.x);
            float2 g0b = __half22float2(*(const __half2*)&ug0.y);
            aL.x = fmaf(pc0.x, l0a.x, aL.x); aL.y = fmaf(pc0.x, l0a.y, aL.y);
            aL.z = fmaf(pc0.x, l0b.x, aL.z); aL.w = fmaf(pc0.x, l0b.y, aL.w);
            aC.x = fmaf(c0, g0a.x, aC.x); aC.y = fmaf(c0, g0a.y, aC.y);
            aC.z = fmaf(c0, g0b.x, aC.z); aC.w = fmaf(c0, g0b.y, aC.w);
            den += pc0.x;
        }
        #pragma unroll
        for (int m = 16; m <= 32; m <<= 1) {
            aL.x += __shfl_xor(aL.x, m, 64); aL.y += __shfl_xor(aL.y, m, 64);
            aL.z += __shfl_xor(aL.z, m, 64); aL.w += __shfl_xor(aL.w, m, 64);
            aC.x += __shfl_xor(aC.x, m, 64); aC.y += __shfl_xor(aC.y, m, 64);
            aC.z += __shfl_xor(aC.z, m, 64); aC.w += __shfl_xor(aC.w, m, 64);
            den  += __shfl_xor(den,  m, 64);
        }
        if (eg == 0) {
            float rd = 1.0f / den;
            float4 la, ga;
            la.x = fmaf(aL.x, rd, gb.x); la.y = fmaf(aL.y, rd, gb.y);
            la.z = fmaf(aL.z, rd, gb.z); la.w = fmaf(aL.w, rd, gb.w);
            la.x = (la.x > 0.f) ? la.x : expm1f(la.x);
            la.y = (la.y > 0.f) ? la.y : expm1f(la.y);
            la.z = (la.z > 0.f) ? la.z : expm1f(la.z);
            la.w = (la.w > 0.f) ? la.w : expm1f(la.w);
            ga.x = fmaxf(fmaf(dd, aC.x, cb.x), 0.f);
            ga.y = fmaxf(fmaf(dd, aC.y, cb.y), 0.f);
            ga.z = fmaxf(fmaf(dd, aC.z, cb.z), 0.f);
            ga.w = fmaxf(fmaf(dd, aC.w, cb.w), 0.f);
            __half2 l01 = __floats2half2_rn(la.x, la.y);
            __half2 l23 = __floats2half2_rn(la.z, la.w);
            __half2 g01h = __floats2half2_rn(ga.x, ga.y);
            __half2 g23h = __floats2half2_rn(ga.z, ga.w);
            catLh[(size_t)n * 16 + (fi >> 2)] =
                make_uint2(*(unsigned int*)&l01, *(unsigned int*)&l23);
            catGh[(size_t)n * 16 + (fi >> 2)] =
                make_uint2(*(unsigned int*)&g01h, *(unsigned int*)&g23h);
        }
    }
}

// ---------------- K4: fusion head, 8 threads x 2 nodes ----------------
// R10 (1 thr/node): 782 waves, w1 loads wave-uniform but serial L1 latency
// -> 70us. R11 (8-way row split, scalar w loads): 8 lines x 1024 load-instrs
// per wave = L1 transaction wall -> 205us. Fix: float4 w1 loads (4x fewer
// instrs) + 2 nodes/thread (w fragment amortized over 2 cat vectors).
// kb loops bounded (#pragma unroll 2) to avoid R9-style VGPR blowup.
__global__ __launch_bounds__(256) void k_fuse(
    const uint2* __restrict__ catLh, const uint2* __restrict__ catGh,
    const float* __restrict__ fus_w1, const float* __restrict__ fus_b1,
    const float* __restrict__ fus_w2, const float* __restrict__ fus_b2,
    float* __restrict__ out)
{
    int idx = blockIdx.x * 256 + threadIdx.x;
    int p = idx >> 3;          // node pair id
    int q = idx & 7;           // 8 hid rows per thread
    if (p >= NN / 2) return;
    int n0 = p * 2, n1 = p * 2 + 1;
    const uint2* rl0 = catLh + (size_t)n0 * 16;
    const uint2* rl1 = catLh + (size_t)n1 * 16;
    const uint2* rg0 = catGh + (size_t)n0 * 16;
    const uint2* rg1 = catGh + (size_t)n1 * 16;
    const float* wbase = fus_w1 + (size_t)(q * 8) * 128;
    float h0[8], h1[8];
    #pragma unroll
    for (int j = 0; j < 8; j++) { float b = fus_b1[q * 8 + j]; h0[j] = b; h1[j] = b; }
    #pragma unroll 2
    for (int kb = 0; kb < 16; kb++) {
        uint2 u0 = rl0[kb], u1 = rl1[kb];
        float2 a0 = __half22float2(*(const __half2*)&u0.x);
        float2 b0 = __half22float2(*(const __half2*)&u0.y);
        float2 a1 = __half22float2(*(const __half2*)&u1.x);
        float2 b1 = __half22float2(*(const __half2*)&u1.y);
        #pragma unroll
        for (int j = 0; j < 8; j++) {
            float4 wv = *(const float4*)(wbase + (size_t)j * 128 + kb * 4);
            h0[j] = fmaf(wv.x, a0.x, h0[j]); h0[j] = fmaf(wv.y, a0.y, h0[j]);
            h0[j] = fmaf(wv.z, b0.x, h0[j]); h0[j] = fmaf(wv.w, b0.y, h0[j]);
            h1[j] = fmaf(wv.x, a1.x, h1[j]); h1[j] = fmaf(wv.y, a1.y, h1[j]);
            h1[j] = fmaf(wv.z, b1.x, h1[j]); h1[j] = fmaf(wv.w, b1.y, h1[j]);
        }
    }
    #pragma unroll 2
    for (int kb = 0; kb < 16; kb++) {
        uint2 u0 = rg0[kb], u1 = rg1[kb];
        float2 a0 = __half22float2(*(const __half2*)&u0.x);
        float2 b0 = __half22float2(*(const __half2*)&u0.y);
        float2 a1 = __half22float2(*(const __half2*)&u1.x);
        float2 b1 = __half22float2(*(const __half2*)&u1.y);
        #pragma unroll
        for (int j = 0; j < 8; j++) {
            float4 wv = *(const float4*)(wbase + (size_t)j * 128 + 64 + kb * 4);
            h0[j] = fmaf(wv.x, a0.x, h0[j]); h0[j] = fmaf(wv.y, a0.y, h0[j]);
            h0[j] = fmaf(wv.z, b0.x, h0[j]); h0[j] = fmaf(wv.w, b0.y, h0[j]);
            h1[j] = fmaf(wv.x, a1.x, h1[j]); h1[j] = fmaf(wv.y, a1.y, h1[j]);
            h1[j] = fmaf(wv.z, b1.x, h1[j]); h1[j] = fmaf(wv.w, b1.y, h1[j]);
        }
    }
    float acc0 = 0.f, acc1 = 0.f;
    #pragma unroll
    for (int j = 0; j < 8; j++) {
        float w2 = fus_w2[q * 8 + j];
        acc0 = fmaf(fmaxf(h0[j], 0.f), w2, acc0);
        acc1 = fmaf(fmaxf(h1[j], 0.f), w2, acc1);
    }
    acc0 += __shfl_xor(acc0, 1, 64); acc1 += __shfl_xor(acc1, 1, 64);
    acc0 += __shfl_xor(acc0, 2, 64); acc1 += __shfl_xor(acc1, 2, 64);
    acc0 += __shfl_xor(acc0, 4, 64); acc1 += __shfl_xor(acc1, 4, 64);
    if (q == 0) {
        float b2 = fus_b2[0];
        out[n0] = acc0 + b2;
        out[n1] = acc1 + b2;
    }
}

extern "C" void kernel_launch(void* const* d_in, const int* in_sizes, int n_in,
                              void* d_out, int out_size, void* d_ws, size_t ws_size,
                              hipStream_t stream)
{
    const float* x_local  = (const float*)d_in[0];
    const float* x_global = (const float*)d_in[1];
    const float* nf       = (const float*)d_in[2];
    const float* coord    = (const float*)d_in[3];
    const int*   ei       = (const int*)d_in[4];
    const float* fc1_w    = (const float*)d_in[5];
    const float* fc1_b    = (const float*)d_in[6];
    const float* fc2_w    = (const float*)d_in[7];
    const float* fc2_b    = (const float*)d_in[8];
    const float* gat_w    = (const float*)d_in[9];
    const float* att_src  = (const float*)d_in[10];
    const float* att_dst  = (const float*)d_in[11];
    const float* gat_b    = (const float*)d_in[12];
    const float* gcn_w    = (const float*)d_in[13];
    const float* gcn_b    = (const float*)d_in[14];
    const float* fus_w1   = (const float*)d_in[15];
    const float* fus_b1   = (const float*)d_in[16];
    const float* fus_w2   = (const float*)d_in[17];
    const float* fus_b2   = (const float*)d_in[18];
    float* out = (float*)d_out;

    char* ws = (char*)d_ws;
    uint2*  rec  = (uint2*) (ws);                       // compact CSR 1.6M*8 = 12,800,000
    __half* xlh  = (__half*)(ws + 12800000);            //  6,400,000
    __half* xgh  = (__half*)(ws + 19200000);            //  6,400,000
    uint2*  catLh= (uint2*) (ws + 25600000);            //  6,400,000
    uint2*  catGh= (uint2*) (ws + 32000000);            //  6,400,000
    // bucket OVERLAYS cat region: dead before k_gather2 writes cat*
    unsigned int* bucket = (unsigned int*)(ws + 25600000); // 8*512*576*4 = 9,437,184
    float4* snode= (float4*)(ws + 38400000);            //    800,000
    float4* dnode= (float4*)(ws + 39200000);            //    800,000
    unsigned int* offA = (unsigned int*)(ws + 40000000);//    200,000
    unsigned int* cntA = (unsigned int*)(ws + 40200000);//    200,000
    float*  dis  = (float*) (ws + 40400000);            //    200,000
    float*  ps   = (float*) (ws + 40600000);            //    200,000
    unsigned int* gcnt = (unsigned int*)(ws + 40800000);//     16,384 -> end ~40.82 MB
    (void)in_sizes; (void)n_in; (void)out_size; (void)ws_size;

    k_zerog<<<(NREP * NBIN + 255) / 256, 256, 0, stream>>>(gcnt);
    k_part2<<<782, 256, 0, stream>>>(ei, bucket, gcnt);   // 782*2048 >= NE
    k_node_gat<<<782, 256, 0, stream>>>(x_local, gat_w, att_src, att_dst,
                                        nf, coord, fc1_w, fc1_b, fc2_w, fc2_b,
                                        xlh, snode, dnode, ps);
    k_node_gcn<<<782, 256, 0, stream>>>(x_global, gcn_w, xgh);
    k_edge3<<<NBIN, 512, 0, stream>>>(bucket, gcnt, snode, dnode,
                                      rec, offA, cntA, dis);
    k_gather2<<<3125, 256, 0, stream>>>(xlh, xgh, ps, dis, offA, cntA, rec,
                                        gat_b, gcn_b, catLh, catGh);
    k_fuse<<<(NN / 2 * 8 + 255) / 256, 256, 0, stream>>>(catLh, catGh,
                                                         fus_w1, fus_b1, fus_w2, fus_b2, out);
}

// Round 13
// 320.379 us; speedup vs baseline: 1.5358x; 1.2881x over previous
//
#include <hip/hip_runtime.h>
#include <hip/hip_fp16.h>
#include <math.h>

#define NN 50000
#define NE 1600000
#define NBIN 512       // fine dst bins; one k_edge3 block owns one bin
#define DSTF 98        // dsts per bin; 512*98 = 50176 >= NN
#define NREP 8         // bucket replicas (XCD-local append regions)
#define PCAP 24        // per-(block,bin) LDS stage cap (mean 4, +10 sigma)
#define BCAPR 576      // per-(rep,bin) bucket cap (mean 391, +9 sigma)

__device__ __forceinline__ float wave_sum(float v) {
    #pragma unroll
    for (int off = 32; off > 0; off >>= 1) v += __shfl_xor(v, off, 64);
    return v;
}

// ---------------- K0a: GAT-side node precompute ----------------
// W in LDS; x tile staged coalesced into LDS; compute reads LDS only.
// t-loop MUST stay rolled (#pragma unroll 1): full unroll exposes 288
// ds_read_b128 whose results LLVM hoists -> >256 VGPR -> scratch spill
// (R8: 849us, R9: 557us, both with GB-scale FETCH/WRITE from spill).
__global__ __launch_bounds__(256) void k_node_gat(
    const float* __restrict__ x_local, const float* __restrict__ gat_w,
    const float* __restrict__ att_src, const float* __restrict__ att_dst,
    const float* __restrict__ nf, const float* __restrict__ coord,
    const float* __restrict__ fc1_w, const float* __restrict__ fc1_b,
    const float* __restrict__ fc2_w, const float* __restrict__ fc2_b,
    __half* __restrict__ xlh,
    float4* __restrict__ snode, float4* __restrict__ dnode,
    float* __restrict__ ps)
{
    __shared__ float wL[64 * 132];              // 33.8 KB W, [h][k] stride 132
    __shared__ float xt[32 * 128];              // 16 KB x tile (32 nodes)
    for (int f = threadIdx.x; f < 64 * 128; f += 256) {
        int h = f >> 7, k = f & 127;
        wL[h * 132 + k] = gat_w[f];
    }
    const int lane = threadIdx.x & 63;
    const int wid  = threadIdx.x >> 6;
    const float asv = att_src[lane];
    const float adv = att_dst[lane];
    const float4* wrow = (const float4*)(wL + lane * 132);
    float4* xts = (float4*)xt;
    const float4* xp = (const float4*)x_local;
    for (int base = blockIdx.x * 32; base < NN; base += gridDim.x * 32) {
        __syncthreads();                        // W staged / prev tile done
        #pragma unroll
        for (int k = 0; k < 4; k++) {
            int gi = base * 32 + (int)threadIdx.x + k * 256;
            if (gi < NN * 32) xts[threadIdx.x + k * 256] = xp[gi];
        }
        __syncthreads();
        float acc[8] = {0.f,0.f,0.f,0.f,0.f,0.f,0.f,0.f};
        const float4* xrow = (const float4*)(xt + wid * 8 * 128);
        #pragma unroll 1
        for (int t = 0; t < 32; t++) {
            float4 wv = wrow[t];                // per-lane ds_read_b128
            #pragma unroll
            for (int j = 0; j < 8; j++) {
                float4 xv = xrow[j * 32 + t];   // wave-uniform LDS broadcast
                acc[j] = fmaf(xv.x, wv.x, acc[j]);
                acc[j] = fmaf(xv.y, wv.y, acc[j]);
                acc[j] = fmaf(xv.z, wv.z, acc[j]);
                acc[j] = fmaf(xv.w, wv.w, acc[j]);
            }
        }
        float sv[8], dv[8];
        #pragma unroll
        for (int j = 0; j < 8; j++) {
            int n = base + wid * 8 + j;
            if (n < NN) xlh[(size_t)n * 64 + lane] = __float2half(acc[j]);
            sv[j] = wave_sum(acc[j] * asv);
            dv[j] = wave_sum(acc[j] * adv);
        }
        if (lane < 8) {
            int n = base + wid * 8 + lane;
            if (n < NN) {
                float svx = (lane==0)?sv[0]:(lane==1)?sv[1]:(lane==2)?sv[2]:(lane==3)?sv[3]
                           :(lane==4)?sv[4]:(lane==5)?sv[5]:(lane==6)?sv[6]:sv[7];
                float dvx = (lane==0)?dv[0]:(lane==1)?dv[1]:(lane==2)?dv[2]:(lane==3)?dv[3]
                           :(lane==4)?dv[4]:(lane==5)?dv[5]:(lane==6)?dv[6]:dv[7];
                float xvv[10];
                #pragma unroll
                for (int k = 0; k < 10; k++) xvv[k] = nf[n * 10 + k];
                float niv = fc2_b[0];
                #pragma unroll
                for (int j = 0; j < 10; j++) {
                    float h = fc1_b[j];
                    #pragma unroll
                    for (int k = 0; k < 10; k++) h = fmaf(xvv[k], fc1_w[j * 10 + k], h);
                    h = (h > 0.f) ? h : expm1f(h);
                    niv = fmaf(h, fc2_w[j], niv);
                }
                float cx = coord[2 * n], cy = coord[2 * n + 1];
                float es = svx + dvx;
                es = (es >= 0.f) ? es : 0.2f * es;
                snode[n] = make_float4(cx, cy, svx, niv);
                dnode[n] = make_float4(cx, cy, dvx, 0.f);
                ps[n] = __expf(es);
            }
        }
    }
}

// ---------------- K0b: GCN-side node precompute ----------------
__global__ __launch_bounds__(256) void k_node_gcn(
    const float* __restrict__ x_global, const float* __restrict__ gcn_w,
    __half* __restrict__ xgh)
{
    __shared__ float wL[64 * 132];
    __shared__ float xt[32 * 128];
    for (int f = threadIdx.x; f < 64 * 128; f += 256) {
        int h = f >> 7, k = f & 127;
        wL[h * 132 + k] = gcn_w[f];
    }
    const int lane = threadIdx.x & 63;
    const int wid  = threadIdx.x >> 6;
    const float4* wrow = (const float4*)(wL + lane * 132);
    float4* xts = (float4*)xt;
    const float4* xp = (const float4*)x_global;
    for (int base = blockIdx.x * 32; base < NN; base += gridDim.x * 32) {
        __syncthreads();
        #pragma unroll
        for (int k = 0; k < 4; k++) {
            int gi = base * 32 + (int)threadIdx.x + k * 256;
            if (gi < NN * 32) xts[threadIdx.x + k * 256] = xp[gi];
        }
        __syncthreads();
        float acc[8] = {0.f,0.f,0.f,0.f,0.f,0.f,0.f,0.f};
        const float4* xrow = (const float4*)(xt + wid * 8 * 128);
        #pragma unroll 1
        for (int t = 0; t < 32; t++) {
            float4 wv = wrow[t];
            #pragma unroll
            for (int j = 0; j < 8; j++) {
                float4 xv = xrow[j * 32 + t];
                acc[j] = fmaf(xv.x, wv.x, acc[j]);
                acc[j] = fmaf(xv.y, wv.y, acc[j]);
                acc[j] = fmaf(xv.z, wv.z, acc[j]);
                acc[j] = fmaf(xv.w, wv.w, acc[j]);
            }
        }
        #pragma unroll
        for (int j = 0; j < 8; j++) {
            int n = base + wid * 8 + j;
            if (n < NN) xgh[(size_t)n * 64 + lane] = __float2half(acc[j]);
        }
    }
}

// ---------------- P0: zero bucket counters ----------------
__global__ __launch_bounds__(256) void k_zerog(unsigned int* __restrict__ gcnt)
{
    int i = blockIdx.x * 256 + threadIdx.x;
    if (i < NREP * NBIN) gcnt[i] = 0u;
}

// ---------------- P1: LDS-staged radix partition into 512 fine bins ------
__global__ __launch_bounds__(256) void k_part2(
    const int* __restrict__ ei,
    unsigned int* __restrict__ bucket, unsigned int* __restrict__ gcnt)
{
    __shared__ unsigned int lcnt[NBIN];
    __shared__ unsigned int lbase[NBIN];
    __shared__ unsigned int lbuf[NBIN][PCAP];   // 512*24*4 = 48 KiB
    const int rep = blockIdx.x & 7;
    for (int t = threadIdx.x; t < NBIN; t += 256) lcnt[t] = 0u;
    __syncthreads();
    const int base = blockIdx.x * 2048;
    #pragma unroll
    for (int k = 0; k < 8; k++) {
        int i = base + k * 256 + threadIdx.x;
        if (i < NE) {
            int d = ei[NE + i];
            int s = ei[i];
            int b = d / DSTF;
            unsigned int pk = (unsigned int)s | ((unsigned int)(d - b * DSTF) << 16);
            unsigned int slot = atomicAdd(&lcnt[b], 1u);
            if (slot < PCAP) {
                lbuf[b][slot] = pk;
            } else {                            // ~never (+10 sigma); insurance
                unsigned int g = atomicAdd(&gcnt[rep * NBIN + b], 1u);
                if (g < BCAPR) bucket[(size_t)(rep * NBIN + b) * BCAPR + g] = pk;
            }
        }
    }
    __syncthreads();
    for (int t = threadIdx.x; t < NBIN; t += 256) {
        unsigned int n = lcnt[t];
        if (n > PCAP) n = PCAP;
        lcnt[t] = n;
        lbase[t] = n ? atomicAdd(&gcnt[rep * NBIN + t], n) : 0u;
    }
    __syncthreads();
    for (int t = threadIdx.x; t < NBIN; t += 256) {
        unsigned int n = lcnt[t];
        unsigned int gb = lbase[t];
        unsigned int* dst = bucket + (size_t)(rep * NBIN + t) * BCAPR;
        for (unsigned int e = 0; e < n; e++) {
            unsigned int g = gb + e;
            if (g < BCAPR) dst[g] = lbuf[t][e];
        }
    }
}

// ---------------- K1: per-bin edge pass, ZERO global atomics -------------
__global__ __launch_bounds__(512) void k_edge3(
    const unsigned int* __restrict__ bucket, const unsigned int* __restrict__ gcnt,
    const float4* __restrict__ snode, const float4* __restrict__ dnode,
    uint2* __restrict__ rec, unsigned int* __restrict__ offA,
    unsigned int* __restrict__ cntA, float* __restrict__ dis)
{
    const int bin = blockIdx.x;
    const int d0  = bin * DSTF;
    __shared__ unsigned int cnt[DSTF], off[DSTF], cur[DSTF], ews[DSTF];
    __shared__ float4 dnd[DSTF];
    __shared__ unsigned int segc[NREP];
    __shared__ unsigned int sm[128];
    __shared__ unsigned int wsum[8];
    __shared__ unsigned int sbase;
    for (int t = threadIdx.x; t < DSTF; t += 512) {
        cnt[t] = 0u; cur[t] = 0u; ews[t] = 0u;
        int d = d0 + t;
        dnd[t] = (d < NN) ? dnode[d] : make_float4(0.f, 0.f, 0.f, 0.f);
    }
    if (threadIdx.x < NREP) {
        unsigned int c = gcnt[threadIdx.x * NBIN + bin];
        segc[threadIdx.x] = (c > BCAPR) ? BCAPR : c;
    }
    unsigned int partial = 0u;
    for (int idx = threadIdx.x; idx < NREP * NBIN; idx += 512) {
        int b = idx & (NBIN - 1);
        if (b < bin) {
            unsigned int c = gcnt[(idx >> 9) * NBIN + b];
            partial += (c > BCAPR) ? BCAPR : c;
        }
    }
    #pragma unroll
    for (int o = 32; o > 0; o >>= 1) partial += __shfl_xor(partial, o, 64);
    if ((threadIdx.x & 63) == 0) wsum[threadIdx.x >> 6] = partial;
    __syncthreads();
    if (threadIdx.x == 0) {
        unsigned int a = 0;
        #pragma unroll
        for (int r = 0; r < 8; r++) a += wsum[r];
        sbase = a;
    }
    __syncthreads();
    #pragma unroll
    for (int r = 0; r < NREP; r++) {
        unsigned int c = segc[r];
        const unsigned int* bk = bucket + (size_t)(r * NBIN + bin) * BCAPR;
        for (unsigned int t = threadIdx.x; t < c; t += 512)
            atomicAdd(&cnt[bk[t] >> 16], 1u);
    }
    __syncthreads();
    if (threadIdx.x < 128) sm[threadIdx.x] = (threadIdx.x < DSTF) ? cnt[threadIdx.x] : 0u;
    __syncthreads();
    for (int o = 1; o < 128; o <<= 1) {
        unsigned int t = 0;
        if (threadIdx.x < 128 && threadIdx.x >= o) t = sm[threadIdx.x - o];
        __syncthreads();
        if (threadIdx.x < 128) sm[threadIdx.x] += t;
        __syncthreads();
    }
    if (threadIdx.x < DSTF) off[threadIdx.x] = sbase + sm[threadIdx.x] - cnt[threadIdx.x];
    __syncthreads();
    #pragma unroll
    for (int r = 0; r < NREP; r++) {
        unsigned int c = segc[r];
        const unsigned int* bk = bucket + (size_t)(r * NBIN + bin) * BCAPR;
        for (unsigned int t = threadIdx.x; t < c; t += 512) {
            unsigned int pk = bk[t];
            int dl = (int)(pk >> 16);
            int s  = (int)(pk & 0xFFFFu);
            float4 sv = snode[s];
            float4 dv = dnd[dl];
            float dx = sv.x - dv.x, dy = sv.y - dv.y;
            float gw = __expf((dx * dx + dy * dy) * (-1.0f / 1800.0f));
            float tt = fmaf(gw, 1.0f + sv.w, -1.0f);
            float sg = 1.0f / (1.0f + __expf(-tt));
            float w  = fmaf(1.9f, sg, 0.1f);
            float e  = sv.z + dv.z;
            e = (e >= 0.f) ? e : 0.2f * e;
            float ewv = (w >= 0.2f) ? w : 0.0f;
            float p = (ewv != 0.f) ? __expf(e) : 0.0f;
            unsigned int rk = atomicAdd(&cur[dl], 1u);
            atomicAdd(&ews[dl], (unsigned int)(ewv * 16777216.0f + 0.5f));
            __half2 h = __floats2half2_rn(p, ewv);
            rec[off[dl] + rk] = make_uint2((unsigned int)s, *(unsigned int*)&h);
        }
    }
    __syncthreads();
    for (int t = threadIdx.x; t < DSTF; t += 512) {
        int d = d0 + t;
        if (d < NN) {
            offA[d] = off[t];
            cntA[d] = cnt[t];
            dis[d]  = rsqrtf(1.0f + (float)ews[t] * (1.0f / 16777216.0f));
        }
    }
}

// ---------------- K3: fused GAT+GCN gather over compact CSR --------------
__global__ __launch_bounds__(256) void k_gather2(
    const __half* __restrict__ xlh, const __half* __restrict__ xgh,
    const float* __restrict__ ps, const float* __restrict__ dis,
    const unsigned int* __restrict__ offA, const unsigned int* __restrict__ cntA,
    const uint2* __restrict__ rec,
    const float* __restrict__ gat_b, const float* __restrict__ gcn_b,
    uint2* __restrict__ catLh, uint2* __restrict__ catGh)
{
    const int lane = threadIdx.x & 63;
    const int wid  = threadIdx.x >> 6;
    const int eg   = lane >> 4;
    const int fi   = (lane & 15) << 2;
    const float4 gb = *(const float4*)(gat_b + fi);
    const float4 cb = *(const float4*)(gcn_b + fi);
    const float g0 = (eg == 0) ? 1.0f : 0.0f;
    for (int n = blockIdx.x * 4 + wid; n < NN; n += gridDim.x * 4) {
        float psv = ps[n] * g0;
        float dd = dis[n];
        int beg = (int)offA[n];
        int end = beg + (int)cntA[n];
        uint2 us = *(const uint2*)(xlh + (size_t)n * 64 + fi);
        uint2 ug = *(const uint2*)(xgh + (size_t)n * 64 + fi);
        float2 s01 = __half22float2(*(const __half2*)&us.x);
        float2 s23 = __half22float2(*(const __half2*)&us.y);
        float2 q01 = __half22float2(*(const __half2*)&ug.x);
        float2 q23 = __half22float2(*(const __half2*)&ug.y);
        float4 aL, aC;
        aL.x = psv * s01.x; aL.y = psv * s01.y; aL.z = psv * s23.x; aL.w = psv * s23.y;
        float sw = dd * g0;
        aC.x = sw * q01.x; aC.y = sw * q01.y; aC.z = sw * q23.x; aC.w = sw * q23.y;
        float den = psv;
        int j = beg + eg;
        for (; j + 4 < end; j += 8) {
            uint2 r0 = rec[j];
            uint2 r1 = rec[j + 4];
            int s0 = (int)r0.x;
            int s1 = (int)r1.x;
            float2 pc0 = __half22float2(*(const __half2*)&r0.y);
            float2 pc1 = __half22float2(*(const __half2*)&r1.y);
            float c0 = dis[s0] * pc0.y;
            float c1 = dis[s1] * pc1.y;
            uint2 ul0 = *(const uint2*)(xlh + (size_t)s0 * 64 + fi);
            uint2 ul1 = *(const uint2*)(xlh + (size_t)s1 * 64 + fi);
            uint2 ug0 = *(const uint2*)(xgh + (size_t)s0 * 64 + fi);
            uint2 ug1 = *(const uint2*)(xgh + (size_t)s1 * 64 + fi);
            float2 l0a = __half22float2(*(const __half2*)&ul0.x);
            float2 l0b = __half22float2(*(const __half2*)&ul0.y);
            float2 l1a = __half22float2(*(const __half2*)&ul1.x);
            float2 l1b = __half22float2(*(const __half2*)&ul1.y);
            float2 g0a = __half22float2(*(const __half2*)&ug0.x);
            float2 g0b = __half22float2(*(const __half2*)&ug0.y);
            float2 g1a = __half22float2(*(const __half2*)&ug1.x);
            float2 g1b = __half22float2(*(const __half2*)&ug1.y);
            aL.x = fmaf(pc0.x, l0a.x, aL.x); aL.y = fmaf(pc0.x, l0a.y, aL.y);
            aL.z = fmaf(pc0.x, l0b.x, aL.z); aL.w = fmaf(pc0.x, l0b.y, aL.w);
            aL.x = fmaf(pc1.x, l1a.x, aL.x); aL.y = fmaf(pc1.x, l1a.y, aL.y);
            aL.z = fmaf(pc1.x, l1b.x, aL.z); aL.w = fmaf(pc1.x, l1b.y, aL.w);
            aC.x = fmaf(c0, g0a.x, aC.x); aC.y = fmaf(c0, g0a.y, aC.y);
            aC.z = fmaf(c0, g0b.x, aC.z); aC.w = fmaf(c0, g0b.y, aC.w);
            aC.x = fmaf(c1, g1a.x, aC.x); aC.y = fmaf(c1, g1a.y, aC.y);
            aC.z = fmaf(c1, g1b.x, aC.z); aC.w = fmaf(c1, g1b.y, aC.w);
            den += pc0.x + pc1.x;
        }
        if (j < end) {
            uint2 r0 = rec[j];
            int s0 = (int)r0.x;
            float2 pc0 = __half22float2(*(const __half2*)&r0.y);
            float c0 = dis[s0] * pc0.y;
            uint2 ul0 = *(const uint2*)(xlh + (size_t)s0 * 64 + fi);
            uint2 ug0 = *(const uint2*)(xgh + (size_t)s0 * 64 + fi);
            float2 l0a = __half22float2(*(const __half2*)&ul0.x);
            float2 l0b = __half22float2(*(const __half2*)&ul0.y);
            float2 g0a = __half22float2(*(const __half2*)&ug0.x);
            float2 g0b = __half22float2(*(const __half2*)&ug0.y);
            aL.x = fmaf(pc0.x, l0a.x, aL.x); aL.y = fmaf(pc0.x, l0a.y, aL.y);
            aL.z = fmaf(pc0.x, l0b.x, aL.z); aL.w = fmaf(pc0.x, l0b.y, aL.w);
            aC.x = fmaf(c0, g0a.x, aC.x); aC.y = fmaf(c0, g0a.y, aC.y);
            aC.z = fmaf(c0, g0b.x, aC.z); aC.w = fmaf(c0, g0b.y, aC.w);
            den += pc0.x;
        }
        #pragma unroll
        for (int m = 16; m <= 32; m <<= 1) {
            aL.x += __shfl_xor(aL.x, m, 64); aL.y += __shfl_xor(aL.y, m, 64);
            aL.z += __shfl_xor(aL.z, m, 64); aL.w += __shfl_xor(aL.w, m, 64);
            aC.x += __shfl_xor(aC.x, m, 64); aC.y += __shfl_xor(aC.y, m, 64);
            aC.z += __shfl_xor(aC.z, m, 64); aC.w += __shfl_xor(aC.w, m, 64);
            den  += __shfl_xor(den,  m, 64);
        }
        if (eg == 0) {
            float rd = 1.0f / den;
            float4 la, ga;
            la.x = fmaf(aL.x, rd, gb.x); la.y = fmaf(aL.y, rd, gb.y);
            la.z = fmaf(aL.z, rd, gb.z); la.w = fmaf(aL.w, rd, gb.w);
            la.x = (la.x > 0.f) ? la.x : expm1f(la.x);
            la.y = (la.y > 0.f) ? la.y : expm1f(la.y);
            la.z = (la.z > 0.f) ? la.z : expm1f(la.z);
            la.w = (la.w > 0.f) ? la.w : expm1f(la.w);
            ga.x = fmaxf(fmaf(dd, aC.x, cb.x), 0.f);
            ga.y = fmaxf(fmaf(dd, aC.y, cb.y), 0.f);
            ga.z = fmaxf(fmaf(dd, aC.z, cb.z), 0.f);
            ga.w = fmaxf(fmaf(dd, aC.w, cb.w), 0.f);
            __half2 l01 = __floats2half2_rn(la.x, la.y);
            __half2 l23 = __floats2half2_rn(la.z, la.w);
            __half2 g01h = __floats2half2_rn(ga.x, ga.y);
            __half2 g23h = __floats2half2_rn(ga.z, ga.w);
            catLh[(size_t)n * 16 + (fi >> 2)] =
                make_uint2(*(unsigned int*)&l01, *(unsigned int*)&l23);
            catGh[(size_t)n * 16 + (fi >> 2)] =
                make_uint2(*(unsigned int*)&g01h, *(unsigned int*)&g23h);
        }
    }
}

// ---------------- K4: fusion head, LDS-staged weights ----------------
// R10: wave-uniform w but 782 waves (0.76/SIMD) -> latency-serial, 70us.
// R11/R12: q-split w from GLOBAL -> 8-line fan-out per load + L1 thrash
// from cat streams -> 205/120us. Fix: stage w1 in LDS once per block
// (32 nodes x 8 q-slices = 256 thr). Bank analysis: w rows q*8+j at
// stride 132 all hit bank 4*(row&7) -> rotate j by q (jj=(q+j)&7) so the
// 8 concurrent rows map to banks {0,4,..,28}: conflict-free. cat staged
// at uint2-stride 33 -> banks 2p+2kb: conflict-free.
__global__ __launch_bounds__(256) void k_fuse(
    const uint2* __restrict__ catLh, const uint2* __restrict__ catGh,
    const float* __restrict__ fus_w1, const float* __restrict__ fus_b1,
    const float* __restrict__ fus_w2, const float* __restrict__ fus_b2,
    float* __restrict__ out)
{
    __shared__ float wS[64 * 132];      // 33.8 KB
    __shared__ uint2 catS[32 * 33];     // 8.4 KB
    const int nb = blockIdx.x * 32;
    for (int f = threadIdx.x; f < 64 * 128; f += 256) {
        int r = f >> 7, c = f & 127;
        wS[r * 132 + c] = fus_w1[f];
    }
    for (int f = threadIdx.x; f < 32 * 32; f += 256) {
        int i = f >> 5, c = f & 31;
        int n = nb + i;
        uint2 v = make_uint2(0u, 0u);
        if (n < NN) v = (c < 16) ? catLh[(size_t)n * 16 + c]
                                 : catGh[(size_t)n * 16 + (c - 16)];
        catS[i * 33 + c] = v;
    }
    __syncthreads();
    const int p = threadIdx.x >> 3;     // local node 0..31
    const int q = threadIdx.x & 7;      // hid slice
    const int n = nb + p;
    float hid[8];
    #pragma unroll
    for (int j = 0; j < 8; j++) {
        int jj = (q + j) & 7;
        hid[j] = fus_b1[q * 8 + jj];
    }
    const uint2* cp = catS + p * 33;
    #pragma unroll 2
    for (int kb = 0; kb < 32; kb++) {   // unified cols: kb*4 covers 0..127
        uint2 u = cp[kb];
        float2 a = __half22float2(*(const __half2*)&u.x);
        float2 b = __half22float2(*(const __half2*)&u.y);
        #pragma unroll
        for (int j = 0; j < 8; j++) {
            int jj = (q + j) & 7;
            float4 wv = *(const float4*)(wS + (size_t)(q * 8 + jj) * 132 + kb * 4);
            hid[j] = fmaf(wv.x, a.x, hid[j]);
            hid[j] = fmaf(wv.y, a.y, hid[j]);
            hid[j] = fmaf(wv.z, b.x, hid[j]);
            hid[j] = fmaf(wv.w, b.y, hid[j]);
        }
    }
    float acc = 0.f;
    #pragma unroll
    for (int j = 0; j < 8; j++) {
        int jj = (q + j) & 7;
        acc = fmaf(fmaxf(hid[j], 0.f), fus_w2[q * 8 + jj], acc);
    }
    acc += __shfl_xor(acc, 1, 64);
    acc += __shfl_xor(acc, 2, 64);
    acc += __shfl_xor(acc, 4, 64);
    if (q == 0 && n < NN) out[n] = acc + fus_b2[0];
}

extern "C" void kernel_launch(void* const* d_in, const int* in_sizes, int n_in,
                              void* d_out, int out_size, void* d_ws, size_t ws_size,
                              hipStream_t stream)
{
    const float* x_local  = (const float*)d_in[0];
    const float* x_global = (const float*)d_in[1];
    const float* nf       = (const float*)d_in[2];
    const float* coord    = (const float*)d_in[3];
    const int*   ei       = (const int*)d_in[4];
    const float* fc1_w    = (const float*)d_in[5];
    const float* fc1_b    = (const float*)d_in[6];
    const float* fc2_w    = (const float*)d_in[7];
    const float* fc2_b    = (const float*)d_in[8];
    const float* gat_w    = (const float*)d_in[9];
    const float* att_src  = (const float*)d_in[10];
    const float* att_dst  = (const float*)d_in[11];
    const float* gat_b    = (const float*)d_in[12];
    const float* gcn_w    = (const float*)d_in[13];
    const float* gcn_b    = (const float*)d_in[14];
    const float* fus_w1   = (const float*)d_in[15];
    const float* fus_b1   = (const float*)d_in[16];
    const float* fus_w2   = (const float*)d_in[17];
    const float* fus_b2   = (const float*)d_in[18];
    float* out = (float*)d_out;

    char* ws = (char*)d_ws;
    uint2*  rec  = (uint2*) (ws);                       // compact CSR 1.6M*8 = 12,800,000
    __half* xlh  = (__half*)(ws + 12800000);            //  6,400,000
    __half* xgh  = (__half*)(ws + 19200000);            //  6,400,000
    uint2*  catLh= (uint2*) (ws + 25600000);            //  6,400,000
    uint2*  catGh= (uint2*) (ws + 32000000);            //  6,400,000
    // bucket OVERLAYS cat region: dead before k_gather2 writes cat*
    unsigned int* bucket = (unsigned int*)(ws + 25600000); // 8*512*576*4 = 9,437,184
    float4* snode= (float4*)(ws + 38400000);            //    800,000
    float4* dnode= (float4*)(ws + 39200000);            //    800,000
    unsigned int* offA = (unsigned int*)(ws + 40000000);//    200,000
    unsigned int* cntA = (unsigned int*)(ws + 40200000);//    200,000
    float*  dis  = (float*) (ws + 40400000);            //    200,000
    float*  ps   = (float*) (ws + 40600000);            //    200,000
    unsigned int* gcnt = (unsigned int*)(ws + 40800000);//     16,384 -> end ~40.82 MB
    (void)in_sizes; (void)n_in; (void)out_size; (void)ws_size;

    k_zerog<<<(NREP * NBIN + 255) / 256, 256, 0, stream>>>(gcnt);
    k_part2<<<782, 256, 0, stream>>>(ei, bucket, gcnt);   // 782*2048 >= NE
    k_node_gat<<<782, 256, 0, stream>>>(x_local, gat_w, att_src, att_dst,
                                        nf, coord, fc1_w, fc1_b, fc2_w, fc2_b,
                                        xlh, snode, dnode, ps);
    k_node_gcn<<<782, 256, 0, stream>>>(x_global, gcn_w, xgh);
    k_edge3<<<NBIN, 512, 0, stream>>>(bucket, gcnt, snode, dnode,
                                      rec, offA, cntA, dis);
    k_gather2<<<3125, 256, 0, stream>>>(xlh, xgh, ps, dis, offA, cntA, rec,
                                        gat_b, gcn_b, catLh, catGh);
    k_fuse<<<(NN + 31) / 32, 256, 0, stream>>>(catLh, catGh,
                                               fus_w1, fus_b1, fus_w2, fus_b2, out);
}